// Round 6
// baseline (249.627 us; speedup 1.0000x reference)
//
#include <hip/hip_runtime.h>
#include <hip/hip_bf16.h>

#define H 768
#define NH 12
#define HD 64
#define FF 3072
#define SQ 1024
#define SKV 1024

typedef __hip_bfloat16 bf16;
typedef __attribute__((ext_vector_type(8))) short short8;   // bf16x8 fragment (guide §3)
typedef __attribute__((ext_vector_type(4))) float f32x4;
typedef __attribute__((ext_vector_type(16))) float f32x16;

__device__ inline void gload16(const void* g, void* l) {
  __builtin_amdgcn_global_load_lds((const __attribute__((address_space(1))) void*)g,
                                   (__attribute__((address_space(3))) void*)l, 16, 0, 0);
}

__device__ inline float bf2f(unsigned short u) {
  unsigned int x = ((unsigned int)u) << 16;
  return __builtin_bit_cast(float, x);
}

// packed bf16 pair: lo -> bits[15:0], hi -> bits[31:16]
__device__ inline unsigned int cvtpk(float lo, float hi) {
  unsigned int r;
  asm("v_cvt_pk_bf16_f32 %0, %1, %2" : "=v"(r) : "v"(lo), "v"(hi));
  return r;
}

// ---------------- fused pre-pass: 2x cvt_bf16 + 5x transpose-convert in one launch ----------------
__device__ inline void cvt_body(const float* __restrict__ src, bf16* __restrict__ dst, int blk) {
  int i = blk * 256 + threadIdx.x;
  float4 v = ((const float4*)src)[i];
  union { unsigned short u[4]; uint2 q; } o;
  bf16 t0 = __float2bfloat16(v.x); o.u[0] = *(unsigned short*)&t0;
  bf16 t1 = __float2bfloat16(v.y); o.u[1] = *(unsigned short*)&t1;
  bf16 t2 = __float2bfloat16(v.z); o.u[2] = *(unsigned short*)&t2;
  bf16 t3 = __float2bfloat16(v.w); o.u[3] = *(unsigned short*)&t3;
  ((uint2*)dst)[i] = o.q;
}

__device__ inline void trans_body(const float* __restrict__ src, bf16* __restrict__ dst,
                                  int Kd, int Nd, int blk, float* tile /*32*33*/) {
  int ntx = Nd >> 5;
  int n0 = (blk % ntx) << 5, k0 = (blk / ntx) << 5;
  int tx = threadIdx.x & 31, ty = threadIdx.x >> 5;  // 32 x 8
#pragma unroll
  for (int i = 0; i < 4; ++i)
    tile[(ty + i * 8) * 33 + tx] = src[(size_t)(k0 + ty + i * 8) * Nd + n0 + tx];
  __syncthreads();
#pragma unroll
  for (int i = 0; i < 4; ++i)
    dst[(size_t)(n0 + ty + i * 8) * Kd + k0 + tx] = __float2bfloat16(tile[tx * 33 + ty + i * 8]);
}

__global__ __launch_bounds__(256) void prep(
    const float* freq, const float* image, bf16* freqb, bf16* imageb,
    const float* Wq, const float* Wk, const float* Wv, const float* W1, const float* W2,
    bf16* WTq, bf16* WTk, bf16* WTv, bf16* W1T, bf16* W2T, int c1) {
  __shared__ float tile[32 * 33];
  int b = blockIdx.x;
  if (b < c1) { cvt_body(freq, freqb, b); return; }
  b -= c1;
  if (b < c1) { cvt_body(image, imageb, b); return; }
  b -= c1;
  const int TQ = (H / 32) * (H / 32);        // 576
  const int T1 = (FF / 32) * (H / 32);       // 2304
  if (b < TQ)            { trans_body(Wq, WTq, H, H, b, tile); return; }
  b -= TQ;
  if (b < TQ)            { trans_body(Wk, WTk, H, H, b, tile); return; }
  b -= TQ;
  if (b < TQ)            { trans_body(Wv, WTv, H, H, b, tile); return; }
  b -= TQ;
  if (b < T1)            { trans_body(W1, W1T, H, FF, b, tile); return; }
  b -= T1;
  trans_body(W2, W2T, FF, H, b, tile);
}

// ---------------- GEMM: C[M,N] = A[M,K] * BT[N,K]^T, 128xBN tile, BK=64 ----------------
// EPI 0: Q-proj  -> out0 bf16 [B*NH][SQ][HD], (x+bias0) * 0.125*log2e  (softmax scale folded)
// EPI 1: KV-proj -> K: out0 bf16 [B*NH][SKV][HD] (n<768, bias0); V: out1 bf16 [B*NH][HD][SKV] (bias1)
// EPI 2: MLP1    -> out0 bf16 [M][N], relu(x+bias0)
// EPI 3: MLP2    -> out0 bf16 [M][N], x+bias0
template <int EPI, int BN>
__global__ __launch_bounds__(256) void gemm_bt(
    const bf16* __restrict__ A, const bf16* __restrict__ BT,
    const float* __restrict__ bias0, const float* __restrict__ bias1,
    void* __restrict__ out0, void* __restrict__ out1, int M, int N, int K) {
  constexpr int SI = BN / 32;   // B-stage iterations (256 thr x 16B each)
  constexpr int JF = BN / 32;   // n-fragments per wave
  __shared__ __align__(16) bf16 lA[128 * 64];
  __shared__ __align__(16) bf16 lB[BN * 64];
  const int t = threadIdx.x;
  const int lane = t & 63, w = t >> 6;
  const int wr = w >> 1, wc = w & 1;
  const int nt = N / BN;
  // T1: bijective XCD chunking on the m-major order (consecutive logicals share A-panel -> same XCD L2)
  const int nwg = gridDim.x;
  int bid = blockIdx.x;
  int logical = ((nwg & 7) == 0) ? ((bid & 7) * (nwg >> 3) + (bid >> 3)) : bid;
  const int m0 = (logical / nt) << 7;
  const int n0 = (logical % nt) * BN;

  const f32x4 fz = {0.f, 0.f, 0.f, 0.f};
  f32x4 acc[4][JF];
#pragma unroll
  for (int i = 0; i < 4; ++i)
#pragma unroll
    for (int j = 0; j < JF; ++j) acc[i][j] = fz;

  for (int kt = 0; kt < K; kt += 64) {
#pragma unroll
    for (int i = 0; i < 4; ++i) {
      int idx = i * 256 + t;
      int row = idx >> 3;
      int chunk = (idx & 7) ^ (row & 7);
      gload16(A + (size_t)(m0 + row) * K + kt + chunk * 8, lA + (size_t)(i * 256 + w * 64) * 8);
    }
#pragma unroll
    for (int i = 0; i < SI; ++i) {
      int idx = i * 256 + t;
      int row = idx >> 3;
      int chunk = (idx & 7) ^ (row & 7);
      gload16(BT + (size_t)(n0 + row) * K + kt + chunk * 8, lB + (size_t)(i * 256 + w * 64) * 8);
    }
    __syncthreads();

    short8 af[2][4], bfv[2][JF];
#pragma unroll
    for (int s = 0; s < 2; ++s) {
#pragma unroll
      for (int i = 0; i < 4; ++i) {
        int ra = wr * 64 + i * 16 + (lane & 15);
        int ca = (s * 4 + (lane >> 4)) ^ (ra & 7);
        af[s][i] = *(const short8*)&lA[ra * 64 + ca * 8];
      }
#pragma unroll
      for (int j = 0; j < JF; ++j) {
        int rb = wc * (BN / 2) + j * 16 + (lane & 15);
        int cb = (s * 4 + (lane >> 4)) ^ (rb & 7);
        bfv[s][j] = *(const short8*)&lB[rb * 64 + cb * 8];
      }
    }
#pragma unroll
    for (int s = 0; s < 2; ++s)
#pragma unroll
      for (int i = 0; i < 4; ++i)
#pragma unroll
        for (int j = 0; j < JF; ++j)
          acc[i][j] = __builtin_amdgcn_mfma_f32_16x16x32_bf16(af[s][i], bfv[s][j], acc[i][j], 0, 0, 0);
    __syncthreads();
  }

  // epilogue (C/D layout: row=(lane>>4)*4+r, col=lane&15 — m89/m91 verified)
#pragma unroll
  for (int i = 0; i < 4; ++i) {
    int mbase = m0 + wr * 64 + i * 16 + ((lane >> 4) << 2);
#pragma unroll
    for (int j = 0; j < JF; ++j) {
      int n = n0 + wc * (BN / 2) + j * 16 + (lane & 15);
#pragma unroll
      for (int r = 0; r < 4; ++r) {
        int m = mbase + r;
        float v = acc[i][j][r];
        if (EPI == 0) {
          v = (v + bias0[n]) * 0.180336880f;  // 0.125 * log2(e): softmax scale + exp2 domain
          int hlin = (m >> 10) * NH + (n >> 6);
          ((bf16*)out0)[((size_t)hlin * SQ + (m & 1023)) * HD + (n & 63)] = __float2bfloat16(v);
        } else if (EPI == 1) {
          int sel = (n >= H);
          int nn = n - (sel ? H : 0);
          v += (sel ? bias1 : bias0)[nn];
          int hlin = (m >> 10) * NH + (nn >> 6);
          if (!sel)
            ((bf16*)out0)[((size_t)hlin * SKV + (m & 1023)) * HD + (nn & 63)] = __float2bfloat16(v);
          else
            ((bf16*)out1)[((size_t)hlin * HD + (nn & 63)) * SKV + (m & 1023)] = __float2bfloat16(v);
        } else if (EPI == 2) {
          v += bias0[n];
          v = fmaxf(v, 0.f);
          ((bf16*)out0)[(size_t)m * N + n] = __float2bfloat16(v);
        } else {
          v += bias0[n];
          ((bf16*)out0)[(size_t)m * N + n] = __float2bfloat16(v);
        }
      }
    }
  }
}

// ---------------- flash attention: 32x32 MFMA, in-register softmax (T12) ----------------
// 1 block = (head, 128 q-rows), 4 waves x 32 q-rows. Q pre-scaled by 0.125*log2e.
// Swapped QK^T: sc = mfma(K, Q) -> lane holds P[q=lane&31][16 kv each of 2 blocks].
// P = exp2(S) with no max tracking (scores O(3) in log2 domain; constant cancels in O/l).
// P -> PV A-fragments fully in-register via v_cvt_pk_bf16_f32 + v_permlane32_swap_b32.
// permlane32_swap semantics (per CDNA4 ISA, analog of permlane16_swap's odd<->even rows):
//   VDST lanes[32:63] <-> SRC0 lanes[0:31].  So swap(vdst=loword, vsrc=hiword) yields
//   post-loword = [own lo-regs | other's hi-regs], post-hiword = [other's lo-regs | own hi-regs].
__global__ __launch_bounds__(256) void attn_fwd(
    const bf16* __restrict__ Q,   // [B*NH][SQ][HD] (pre-scaled)
    const bf16* __restrict__ Kg_, // [B*NH][SKV][HD]
    const bf16* __restrict__ VT,  // [B*NH][HD][SKV]
    bf16* __restrict__ ctx, int nblk) {  // [B][SQ][H] bf16
  __shared__ __align__(16) bf16 Qs[128 * 64];
  __shared__ __align__(16) bf16 Ks[2][64 * 64];
  __shared__ __align__(16) bf16 Vs[2][64 * 64];

  const int t = threadIdx.x, lane = t & 63, w = t >> 6;
  const int hi = lane >> 5, l31 = lane & 31;
  int bid = blockIdx.x;
  int logical = ((nblk & 7) == 0) ? (bid & 7) * (nblk >> 3) + (bid >> 3) : bid;
  const int hl = logical >> 3;          // SQ/128 = 8 q-blocks per head
  const int q0 = (logical & 7) << 7;
  const bf16* Qg = Q + ((size_t)hl * SQ + q0) * HD;
  const bf16* Kg = Kg_ + (size_t)hl * SKV * HD;
  const bf16* Vg = VT + (size_t)hl * HD * SKV;

  // stage Q (128x64): 1024 slots x 16B; swizzled source / linear dest (G21)
#pragma unroll
  for (int rep = 0; rep < 4; ++rep) {
    int slot = rep * 256 + t;
    int row = slot >> 3, chunk = (slot & 7) ^ (row & 7);
    gload16(Qg + (size_t)row * HD + chunk * 8, (char*)Qs + (size_t)slot * 16);
  }
  // stage K0, V0 (64x64 each: 512 slots -> 2 per thread)
#pragma unroll
  for (int rep = 0; rep < 2; ++rep) {
    int slot = rep * 256 + t;
    int row = slot >> 3, chunk = (slot & 7) ^ (row & 7);
    gload16(Kg + (size_t)row * HD + chunk * 8, (char*)&Ks[0][0] + (size_t)slot * 16);
    gload16(Vg + (size_t)row * SKV + chunk * 8, (char*)&Vs[0][0] + (size_t)slot * 16);
  }
  __syncthreads();  // Q,K0,V0 landed

  // Q fragments (B-operand of swapped QK^T): col=q=lane&31, k=d=ks*16+hi*8+e
  short8 aq[4];
#pragma unroll
  for (int ks = 0; ks < 4; ++ks) {
    int row = w * 32 + l31;
    int chunk = (ks * 2 + hi) ^ (row & 7);
    aq[ks] = *(const short8*)&Qs[row * 64 + chunk * 8];
  }

  f32x16 oa0, oa1;
#pragma unroll
  for (int r = 0; r < 16; ++r) { oa0[r] = 0.f; oa1[r] = 0.f; }
  float ls0 = 0.f, ls1 = 0.f;

#pragma unroll 2
  for (int i = 0; i < 16; ++i) {
    const int buf = i & 1;
    if (i < 15) {  // prefetch next K/V tile into buf^1 (in flight across the compute)
      int kvn = (i + 1) << 6;
#pragma unroll
      for (int rep = 0; rep < 2; ++rep) {
        int slot = rep * 256 + t;
        int row = slot >> 3, chunk = (slot & 7) ^ (row & 7);
        gload16(Kg + (size_t)(kvn + row) * HD + chunk * 8, (char*)&Ks[buf ^ 1][0] + (size_t)slot * 16);
        gload16(Vg + (size_t)row * SKV + kvn + chunk * 8, (char*)&Vs[buf ^ 1][0] + (size_t)slot * 16);
      }
    }

    // S^T = mfma(K, Q): sc{0,1}[r] = S[q=l31][kv = 32n + (r&3)+8*(r>>2)+4*hi]
    f32x16 sc0, sc1;
#pragma unroll
    for (int r = 0; r < 16; ++r) { sc0[r] = 0.f; sc1[r] = 0.f; }
    __builtin_amdgcn_s_setprio(1);
#pragma unroll
    for (int ks = 0; ks < 4; ++ks) {
      int c0 = ks * 2 + hi;
      int r0 = l31;
      short8 kf0 = *(const short8*)&Ks[buf][r0 * 64 + (c0 ^ (r0 & 7)) * 8];
      sc0 = __builtin_amdgcn_mfma_f32_32x32x16_bf16(kf0, aq[ks], sc0, 0, 0, 0);
      int r1 = 32 + l31;
      short8 kf1 = *(const short8*)&Ks[buf][r1 * 64 + (c0 ^ (r1 & 7)) * 8];
      sc1 = __builtin_amdgcn_mfma_f32_32x32x16_bf16(kf1, aq[ks], sc1, 0, 0, 0);
    }
    __builtin_amdgcn_s_setprio(0);

    // P = exp2(S) in-register; accumulate l
#pragma unroll
    for (int r = 0; r < 16; ++r) { sc0[r] = exp2f(sc0[r]); ls0 += sc0[r]; }
#pragma unroll
    for (int r = 0; r < 16; ++r) { sc1[r] = exp2f(sc1[r]); ls1 += sc1[r]; }

    // PA fragments: pa[k4] = P[q=lane&31][kv=16*k4 + hi*8 + e], e=0..7
    // word0/1 = [own sc(b..b+3) | other sc(b..b+3)]; word2/3 = [other sc(b+4..b+7) | own sc(b+4..b+7)]
    // via swap(vdst=low-word, vsrc=high-word)  (vdst.hi <-> vsrc.lo)
    short8 pa[4];
#pragma unroll
    for (int k4 = 0; k4 < 4; ++k4) {
      const int base = (k4 & 1) * 8;
      unsigned int p0, p1, qq0, qq1;
      if (k4 & 2) {
        p0 = cvtpk(sc1[base + 0], sc1[base + 1]);
        p1 = cvtpk(sc1[base + 2], sc1[base + 3]);
        qq0 = cvtpk(sc1[base + 4], sc1[base + 5]);
        qq1 = cvtpk(sc1[base + 6], sc1[base + 7]);
      } else {
        p0 = cvtpk(sc0[base + 0], sc0[base + 1]);
        p1 = cvtpk(sc0[base + 2], sc0[base + 3]);
        qq0 = cvtpk(sc0[base + 4], sc0[base + 5]);
        qq1 = cvtpk(sc0[base + 6], sc0[base + 7]);
      }
      // swap(vdst=p, vsrc=qq): p.hi <- qq.lo(other half), qq.lo <- p.hi(other half)
      asm volatile("v_permlane32_swap_b32 %0, %1" : "+v"(p0), "+v"(qq0));
      asm volatile("v_permlane32_swap_b32 %0, %1" : "+v"(p1), "+v"(qq1));
      union { unsigned int u[4]; short8 s8; } pu;
      pu.u[0] = p0; pu.u[1] = p1; pu.u[2] = qq0; pu.u[3] = qq1;
      pa[k4] = pu.s8;
    }

    // O += P V (V^T tile: B[k=kv][col=d] read from Vs[d][kv])
    __builtin_amdgcn_s_setprio(1);
#pragma unroll
    for (int k4 = 0; k4 < 4; ++k4) {
      int cc = k4 * 2 + hi;
      int r0 = l31;
      short8 vf0 = *(const short8*)&Vs[buf][r0 * 64 + (cc ^ (r0 & 7)) * 8];
      oa0 = __builtin_amdgcn_mfma_f32_32x32x16_bf16(pa[k4], vf0, oa0, 0, 0, 0);
      int r1 = 32 + l31;
      short8 vf1 = *(const short8*)&Vs[buf][r1 * 64 + (cc ^ (r1 & 7)) * 8];
      oa1 = __builtin_amdgcn_mfma_f32_32x32x16_bf16(pa[k4], vf1, oa1, 0, 0, 0);
    }
    __builtin_amdgcn_s_setprio(0);

    __syncthreads();  // all waves done with buf; prefetch into buf^1 drained here
  }

  // l[q=lane&31] = own half-sum + other half's; gather per output row via shfl
  float lt = (ls0 + ls1) + __shfl_xor(ls0 + ls1, 32);
  float rlq = 1.0f / lt;
  const int b = hl / NH, hh = hl % NH;
  bf16* outp = ctx + ((size_t)b * SQ + q0 + w * 32) * H + hh * HD;
#pragma unroll
  for (int r = 0; r < 16; ++r) {
    int qo = (r & 3) + 8 * (r >> 2) + 4 * hi;
    float rv = __shfl(rlq, qo);
    bf16* rowp = outp + (size_t)qo * H;
    rowp[l31]      = __float2bfloat16(oa0[r] * rv);
    rowp[32 + l31] = __float2bfloat16(oa1[r] * rv);
  }
}

// ---------------- residual + post-LN: o = res + LN(x)*g + beta (x bf16, vectorized) ----------------
__global__ __launch_bounds__(256) void ln_res(
    const bf16* __restrict__ x, const float* __restrict__ res,
    const float* __restrict__ g, const float* __restrict__ beta,
    float* __restrict__ o32, bf16* __restrict__ ob, int write_b) {
  const int row = blockIdx.x;
  const int t = threadIdx.x;
  float v[4];
  float s = 0.f, s2 = 0.f;
  if (t < 192) {
    ushort4 xv = ((const ushort4*)(x + (size_t)row * H))[t];
    v[0] = bf2f(xv.x); v[1] = bf2f(xv.y); v[2] = bf2f(xv.z); v[3] = bf2f(xv.w);
#pragma unroll
    for (int k = 0; k < 4; ++k) { s += v[k]; s2 += v[k] * v[k]; }
  } else {
#pragma unroll
    for (int k = 0; k < 4; ++k) v[k] = 0.f;
  }
#pragma unroll
  for (int off = 32; off > 0; off >>= 1) {
    s += __shfl_down(s, off);
    s2 += __shfl_down(s2, off);
  }
  __shared__ float red[8];
  if ((t & 63) == 0) { red[t >> 6] = s; red[4 + (t >> 6)] = s2; }
  __syncthreads();
  float st = red[0] + red[1] + red[2] + red[3];
  float s2t = red[4] + red[5] + red[6] + red[7];
  float mean = st * (1.f / 768.f);
  float var = s2t * (1.f / 768.f) - mean * mean;
  float rs = rsqrtf(var + 1e-5f);
  if (t < 192) {
    float4 rv = ((const float4*)(res + (size_t)row * H))[t];
    float4 gv = ((const float4*)g)[t];
    float4 bv = ((const float4*)beta)[t];
    float4 o;
    o.x = rv.x + (v[0] - mean) * rs * gv.x + bv.x;
    o.y = rv.y + (v[1] - mean) * rs * gv.y + bv.y;
    o.z = rv.z + (v[2] - mean) * rs * gv.z + bv.z;
    o.w = rv.w + (v[3] - mean) * rs * gv.w + bv.w;
    ((float4*)(o32 + (size_t)row * H))[t] = o;
    if (write_b) {
      union { unsigned short u[4]; uint2 q; } ob4;
      bf16 b0 = __float2bfloat16(o.x); ob4.u[0] = *(unsigned short*)&b0;
      bf16 b1 = __float2bfloat16(o.y); ob4.u[1] = *(unsigned short*)&b1;
      bf16 b2 = __float2bfloat16(o.z); ob4.u[2] = *(unsigned short*)&b2;
      bf16 b3 = __float2bfloat16(o.w); ob4.u[3] = *(unsigned short*)&b3;
      ((uint2*)(ob + (size_t)row * H))[t] = ob4.q;
    }
  }
}

extern "C" void kernel_launch(void* const* d_in, const int* in_sizes, int n_in,
                              void* d_out, int out_size, void* d_ws, size_t ws_size,
                              hipStream_t stream) {
  const float* freq  = (const float*)d_in[0];
  const float* image = (const float*)d_in[1];
  const float* Wq = (const float*)d_in[2];
  const float* bq = (const float*)d_in[3];
  const float* Wk = (const float*)d_in[4];
  const float* bk = (const float*)d_in[5];
  const float* Wv = (const float*)d_in[6];
  const float* bv = (const float*)d_in[7];
  const float* g1 = (const float*)d_in[8];
  const float* be1 = (const float*)d_in[9];
  const float* g2 = (const float*)d_in[10];
  const float* be2 = (const float*)d_in[11];
  const float* W1 = (const float*)d_in[12];
  const float* b1 = (const float*)d_in[13];
  const float* W2 = (const float*)d_in[14];
  const float* b2 = (const float*)d_in[15];

  const int Bc = in_sizes[0] / (SQ * H);  // 8
  const int M = Bc * SQ;                  // 8192

  char* p = (char*)d_ws;
  bf16* W1T = (bf16*)p;  p += (size_t)FF * H * 2;
  bf16* W2T = (bf16*)p;  p += (size_t)H * FF * 2;
  bf16* ctxb = (bf16*)p; p += (size_t)M * H * 2;   // attn out (bf16); reused for mlp2 out
  float* h32 = (float*)p; p += (size_t)M * H * 4;
  bf16* hb = (bf16*)p;   p += (size_t)M * H * 2;
  char* U = p;  // union region
  bf16* freqb = (bf16*)U;
  bf16* imageb = (bf16*)(U + (size_t)M * H * 2);
  bf16* WTq   = (bf16*)(U + (size_t)2 * M * H * 2);
  bf16* WTkv  = (bf16*)(U + (size_t)2 * M * H * 2 + (size_t)H * H * 2);
  bf16* Qb    = (bf16*)(U + (size_t)2 * M * H * 2 + (size_t)3 * H * H * 2);
  bf16* Kbuf  = (bf16*)((char*)Qb + (size_t)M * H * 2);
  bf16* VTb   = (bf16*)((char*)Kbuf + (size_t)M * H * 2);
  bf16* mlp1  = (bf16*)U;    // reused after attention consumed Q/K/VT
  bf16* mlp2b = ctxb;        // reused after first ln_res consumed ctxb

  // fused pre-pass: c1 blocks per cvt, then 3x576 + 2x2304 transpose tiles
  int c1 = M * H / 1024;
  int nprep = 2 * c1 + 3 * ((H / 32) * (H / 32)) + (FF / 32) * (H / 32) + (H / 32) * (FF / 32);
  prep<<<nprep, 256, 0, stream>>>(freq, image, freqb, imageb,
                                  Wq, Wk, Wv, W1, W2,
                                  WTq, WTkv, WTkv + (size_t)H * H, W1T, W2T, c1);

  gemm_bt<0, 64><<<(M / 128) * (H / 64), 256, 0, stream>>>(freqb, WTq, bq, nullptr, Qb, nullptr, M, H, H);
  gemm_bt<1, 128><<<(M / 128) * (2 * H / 128), 256, 0, stream>>>(imageb, WTkv, bk, bv, Kbuf, VTb, M, 2 * H, H);
  int nblk = Bc * NH * (SQ / 128);
  attn_fwd<<<nblk, 256, 0, stream>>>(Qb, Kbuf, VTb, ctxb, nblk);
  ln_res<<<M, 256, 0, stream>>>(ctxb, freq, g1, be1, h32, hb, 1);
  gemm_bt<2, 128><<<(M / 128) * (FF / 128), 256, 0, stream>>>(hb, W1T, b1, nullptr, mlp1, nullptr, M, FF, H);
  gemm_bt<3, 64><<<(M / 128) * (H / 64), 256, 0, stream>>>(mlp1, W2T, b2, nullptr, mlp2b, nullptr, M, H, FF);
  ln_res<<<M, 256, 0, stream>>>(mlp2b, h32, g2, be2, (float*)d_out, nullptr, 0);
}